// Round 5
// baseline (255.157 us; speedup 1.0000x reference)
//
#include <hip/hip_runtime.h>
#include <hip/hip_bf16.h>

#define NN 20000
#define GG 128

typedef __bf16 bf16x8_t __attribute__((ext_vector_type(8)));
typedef float  f32x4_t  __attribute__((ext_vector_type(4)));
typedef __hip_bfloat16 hbf16;

// packed-weight table in ws (bf16-element offsets)
#define PK_NPW1 0       // 32768 : npW1 B-frags (16 ct x 4 kb x 64 lane x 8)
#define PK_PPW1 32768   // 16384 : ppW1 (8 ct x 4 kb x 64 x 8)
#define PK_NPW2 49152   //  4096 : npW2 (8 kb x 64 x 8), cols>=12 zero
#define PK_PPW2 53248   //  2048 : ppW2 (4 kb x 64 x 8), cols>=3 zero
#define PK_WN   55296   //  4096 : Wn   (8 ct x 64 x 8), K padded 12->32
// total 59392 bf16

__device__ __forceinline__ float silu_f(float v) {
    return v / (1.0f + expf(-v));
}

// ---------------------------------------------------------------------------
// Kernel 1: pack weights into MFMA B-fragment order.  232 blocks x 256 = 59392.
// ---------------------------------------------------------------------------
__global__ __launch_bounds__(256) void pack_kernel(
        const float* __restrict__ npW1, const float* __restrict__ npW2,
        const float* __restrict__ ppW1, const float* __restrict__ ppW2,
        const float* __restrict__ Wn, hbf16* __restrict__ wsb) {
    const int s = blockIdx.x * 256 + threadIdx.x;
    if (s < 32768) {                       // npW1: [128,256]
        const int p = s;
        const int j = p & 7, l = (p >> 3) & 63, kb = (p >> 9) & 3, ct = p >> 11;
        const int k = kb * 32 + ((l >> 4) << 3) + j;
        const int n = ct * 16 + (l & 15);
        wsb[PK_NPW1 + p] = __float2bfloat16(npW1[k * 256 + n]);
    } else if (s < 49152) {                // ppW1: [128,128]
        const int p = s - 32768;
        const int j = p & 7, l = (p >> 3) & 63, kb = (p >> 9) & 3, ct = p >> 11;
        const int k = kb * 32 + ((l >> 4) << 3) + j;
        const int n = ct * 16 + (l & 15);
        wsb[PK_PPW1 + p] = __float2bfloat16(ppW1[k * 128 + n]);
    } else if (s < 53248) {                // npW2: [256,12] -> padded N=16
        const int p = s - 49152;
        const int j = p & 7, l = (p >> 3) & 63, kb = p >> 9;
        const int k = kb * 32 + ((l >> 4) << 3) + j;
        const int n = l & 15;
        wsb[PK_NPW2 + p] = __float2bfloat16(n < 12 ? npW2[k * 12 + n] : 0.0f);
    } else if (s < 55296) {                // ppW2: [128,3] -> padded N=16
        const int p = s - 53248;
        const int j = p & 7, l = (p >> 3) & 63, kb = p >> 9;
        const int k = kb * 32 + ((l >> 4) << 3) + j;
        const int n = l & 15;
        wsb[PK_PPW2 + p] = __float2bfloat16(n < 3 ? ppW2[k * 3 + n] : 0.0f);
    } else {                               // Wn: [12,128] -> K padded to 32
        const int p = s - 55296;
        const int j = p & 7, l = (p >> 3) & 63, ct = p >> 9;
        const int k = ((l >> 4) << 3) + j;
        const int n = ct * 16 + (l & 15);
        wsb[PK_WN + p] = __float2bfloat16(k < 12 ? Wn[k * 128 + n] : 0.0f);
    }
}

// ---------------------------------------------------------------------------
// Kernel 2: fully fused.  313 blocks x 256 threads; each block owns 64 nodes.
// Phase A: compute gadd for the <=4 graphs this block's nodes touch (batch is
//          sorted; redundant across blocks but fully parallel).
// Phase B: wave-autonomous MFMA node MLPs (r4 structure), gadd from LDS.
// MFMA contract (16x16x32 bf16), q=lane>>4, r=lane&15:
//   A[m=r][k=q*8+j]   B[k=q*8+j][n=r]   D[m=q*4+i][n=r]
// ---------------------------------------------------------------------------
__global__ __launch_bounds__(256) void fused_kernel(
        const float* __restrict__ x, const int* __restrict__ batch,
        const float* __restrict__ t, const float* __restrict__ topo,
        const float* __restrict__ stab, const float* __restrict__ sust,
        const float* __restrict__ tmW1, const float* __restrict__ tmb1,
        const float* __restrict__ tmW2, const float* __restrict__ tmb2,
        const float* __restrict__ topoW1, const float* __restrict__ topob1,
        const float* __restrict__ topoW2, const float* __restrict__ topob2,
        const float* __restrict__ stabW1, const float* __restrict__ stabb1,
        const float* __restrict__ stabW2, const float* __restrict__ stabb2,
        const float* __restrict__ sustW1, const float* __restrict__ sustb1,
        const float* __restrict__ sustW2, const float* __restrict__ sustb2,
        const float* __restrict__ combW1, const float* __restrict__ combb1,
        const float* __restrict__ combW2, const float* __restrict__ combb2,
        const float* __restrict__ Wv, const float* __restrict__ Wo,
        const float* __restrict__ bo, const float* __restrict__ bn,
        const float* __restrict__ npb1, const float* __restrict__ npb2,
        const float* __restrict__ ppb1, const float* __restrict__ ppb2,
        const hbf16* __restrict__ wsb,
        float* __restrict__ out) {
    __shared__ float s_te[128];
    __shared__ float s_th1[256];
    __shared__ float s_tef[128];
    __shared__ float s_l1[64];
    __shared__ float s_cat[64];
    __shared__ float s_c1[64];
    __shared__ float s_cond[64];
    __shared__ float s_v[128];
    __shared__ float s_red[256];
    __shared__ float s_gadd[4][128];
    __shared__ __align__(16) hbf16 tbuf[4 * 16 * 264];  // per-wave h/z1/z2 buffer

    const int tid = threadIdx.x;
    const int nb = blockIdx.x * 64;
    const int nlast = (nb + 63 < NN) ? nb + 63 : NN - 1;

    const int g0 = batch[nb];
    const int g1 = batch[nlast];
    int ng = g1 - g0 + 1;
    if (ng > 4) ng = 4;

    // ======================= Phase A: per-graph gadd =======================
    for (int gi = 0; gi < ng; ++gi) {
        const int g = g0 + gi;

        // time embedding (tid<128) + cond layer1 (tid in [128,192))
        if (tid < 128) {
            const float tval = t[g];
            const int i = tid & 63;
            const float fr = expf(-(float)i * 0.14619587892025688f);
            const float arg = tval * fr;
            s_te[tid] = (tid < 64) ? sinf(arg) : cosf(arg);
        } else if (tid < 192) {
            const int c = tid - 128;
            if (c < 32) {
                float acc = topob1[c];
                for (int k = 0; k < 7; ++k)
                    acc += topo[g * 7 + k] * topoW1[k * 32 + c];
                s_l1[c] = silu_f(acc);
            } else if (c < 48) {
                const int j = c - 32;
                float acc = stabb1[j];
                for (int k = 0; k < 2; ++k)
                    acc += stab[g * 2 + k] * stabW1[k * 16 + j];
                s_l1[c] = silu_f(acc);
            } else {
                const int j = c - 48;
                float acc = sustb1[j];
                for (int k = 0; k < 3; ++k)
                    acc += sust[g * 3 + k] * sustW1[k * 16 + j];
                s_l1[c] = silu_f(acc);
            }
        }
        __syncthreads();

        // time MLP layer 1 [128]->[256]
        {
            float acc = tmb1[tid];
#pragma unroll 4
            for (int k = 0; k < 128; ++k)
                acc += s_te[k] * tmW1[k * 256 + tid];
            s_th1[tid] = silu_f(acc);
        }
        __syncthreads();

        // time MLP layer 2 [256]->[128], split-k 2-way
        {
            const int j = tid & 127, half = tid >> 7;
            float acc = 0.0f;
#pragma unroll 4
            for (int kk = 0; kk < 128; ++kk)
                acc += s_th1[half * 128 + kk] * tmW2[(half * 128 + kk) * 128 + j];
            s_red[tid] = acc;
        }
        __syncthreads();

        // finish tef + cond layer2
        if (tid < 128) {
            s_tef[tid] = tmb2[tid] + s_red[tid] + s_red[tid + 128];
        } else if (tid < 192) {
            const int c = tid - 128;
            if (c < 32) {
                float acc = topob2[c];
                for (int k = 0; k < 32; ++k)
                    acc += s_l1[k] * topoW2[k * 32 + c];
                s_cat[c] = acc;
            } else if (c < 48) {
                const int j = c - 32;
                float acc = stabb2[j];
                for (int k = 0; k < 16; ++k)
                    acc += s_l1[32 + k] * stabW2[k * 16 + j];
                s_cat[c] = acc;
            } else {
                const int j = c - 48;
                float acc = sustb2[j];
                for (int k = 0; k < 16; ++k)
                    acc += s_l1[48 + k] * sustW2[k * 16 + j];
                s_cat[c] = acc;
            }
        }
        __syncthreads();

        // comb layer 1 [64]->[64], split-k 4-way
        {
            const int j = tid & 63, part = tid >> 6;
            float acc = 0.0f;
#pragma unroll
            for (int kk = 0; kk < 16; ++kk)
                acc += s_cat[part * 16 + kk] * combW1[(part * 16 + kk) * 64 + j];
            s_red[tid] = acc;
        }
        __syncthreads();
        if (tid < 64)
            s_c1[tid] = silu_f(combb1[tid] + s_red[tid] + s_red[tid + 64] +
                               s_red[tid + 128] + s_red[tid + 192]);
        __syncthreads();

        // comb layer 2 [64]->[64], split-k 4-way
        {
            const int j = tid & 63, part = tid >> 6;
            float acc = 0.0f;
#pragma unroll
            for (int kk = 0; kk < 16; ++kk)
                acc += s_c1[part * 16 + kk] * combW2[(part * 16 + kk) * 64 + j];
            s_red[tid] = acc;
        }
        __syncthreads();
        if (tid < 64)
            s_cond[tid] = combb2[tid] + s_red[tid] + s_red[tid + 64] +
                          s_red[tid + 128] + s_red[tid + 192];
        __syncthreads();

        // v = cond @ Wv, split-k 2-way
        {
            const int j = tid & 127, half = tid >> 7;
            float acc = 0.0f;
#pragma unroll
            for (int kk = 0; kk < 32; ++kk)
                acc += s_cond[half * 32 + kk] * Wv[(half * 32 + kk) * 128 + j];
            s_red[tid] = acc;
        }
        __syncthreads();
        if (tid < 128) s_v[tid] = s_red[tid] + s_red[tid + 128];
        __syncthreads();

        // a = v @ Wo + bo ; gadd = 6*(a + silu(tef))
        {
            const int j = tid & 127, half = tid >> 7;
            float acc = 0.0f;
#pragma unroll 4
            for (int kk = 0; kk < 64; ++kk)
                acc += s_v[half * 64 + kk] * Wo[(half * 64 + kk) * 128 + j];
            s_red[tid] = acc;
        }
        __syncthreads();
        if (tid < 128)
            s_gadd[gi][tid] =
                6.0f * (bo[tid] + s_red[tid] + s_red[tid + 128] + silu_f(s_tef[tid]));
        __syncthreads();
    }

    // ======================= Phase B: node MLPs (per-wave) =================
    const int w    = tid >> 6;
    const int lane = tid & 63;
    const int q    = lane >> 4;
    const int r    = lane & 15;
    const int n16  = nb + w * 16;

    hbf16* wb = tbuf + w * (16 * 264);

    // A-frag of x (M=16 nodes, K=12 padded to 32)
    bf16x8_t Ax;
    {
        const int node = n16 + r;
        float xv[8];
#pragma unroll
        for (int j = 0; j < 8; ++j) xv[j] = 0.0f;
        if (node < NN) {
            if (q == 0) {
                const float4 a = *reinterpret_cast<const float4*>(x + node * 12);
                const float4 b = *reinterpret_cast<const float4*>(x + node * 12 + 4);
                xv[0] = a.x; xv[1] = a.y; xv[2] = a.z; xv[3] = a.w;
                xv[4] = b.x; xv[5] = b.y; xv[6] = b.z; xv[7] = b.w;
            } else if (q == 1) {
                const float4 a = *reinterpret_cast<const float4*>(x + node * 12 + 8);
                xv[0] = a.x; xv[1] = a.y; xv[2] = a.z; xv[3] = a.w;
            }
        }
#pragma unroll
        for (int j = 0; j < 8; ++j) {
            const hbf16 tv = __float2bfloat16(xv[j]);
            Ax[j] = *reinterpret_cast<const __bf16*>(&tv);
        }
    }

    // graph index (within s_gadd) for the 4 node-rows this lane owns
    int gidx[4];
#pragma unroll
    for (int i = 0; i < 4; ++i) {
        const int gn = n16 + q * 4 + i;
        int b = (gn < NN) ? batch[gn] : g0;
        int d = b - g0;
        if (d < 0) d = 0;
        if (d > ng - 1) d = ng - 1;
        gidx[i] = d;
    }

    // h = x@Wn (MFMA) + bn + gadd  -> wb stride 136
    {
        f32x4_t hacc[8];
#pragma unroll
        for (int ct = 0; ct < 8; ++ct) {
            const bf16x8_t Bf = *reinterpret_cast<const bf16x8_t*>(
                &wsb[PK_WN + (ct * 64 + lane) * 8]);
            hacc[ct] = __builtin_amdgcn_mfma_f32_16x16x32_bf16(
                Ax, Bf, (f32x4_t){0.f, 0.f, 0.f, 0.f}, 0, 0, 0);
        }
#pragma unroll
        for (int ct = 0; ct < 8; ++ct) {
            const int n = ct * 16 + r;
            const float bv = bn[n];
#pragma unroll
            for (int i = 0; i < 4; ++i) {
                const float hv = hacc[ct][i] + bv + s_gadd[gidx[i]][n];
                wb[(q * 4 + i) * 136 + n] = __float2bfloat16(hv);
            }
        }
    }

    // read h back as A-frags (K=128 -> 4 kb); h region then dead
    bf16x8_t Ah[4];
#pragma unroll
    for (int kb = 0; kb < 4; ++kb)
        Ah[kb] = *reinterpret_cast<const bf16x8_t*>(
            &wb[r * 136 + kb * 32 + q * 8]);

    // np L1: z1 = silu(h @ npW1 + npb1) -> wb stride 264
    {
        f32x4_t acc[16];
#pragma unroll
        for (int ct = 0; ct < 16; ++ct) acc[ct] = (f32x4_t){0.f, 0.f, 0.f, 0.f};
#pragma unroll
        for (int kb = 0; kb < 4; ++kb) {
#pragma unroll
            for (int ct = 0; ct < 16; ++ct) {
                const bf16x8_t Bf = *reinterpret_cast<const bf16x8_t*>(
                    &wsb[PK_NPW1 + ((ct * 4 + kb) * 64 + lane) * 8]);
                acc[ct] = __builtin_amdgcn_mfma_f32_16x16x32_bf16(
                    Ah[kb], Bf, acc[ct], 0, 0, 0);
            }
        }
#pragma unroll
        for (int ct = 0; ct < 16; ++ct) {
            const int col = ct * 16 + r;
            const float b1 = npb1[col];
#pragma unroll
            for (int i = 0; i < 4; ++i)
                wb[(q * 4 + i) * 264 + col] =
                    __float2bfloat16(silu_f(acc[ct][i] + b1));
        }
    }

    // np L2: node_pred = z1 @ npW2 + npb2 (K=256 -> 8 kb)
    {
        f32x4_t acc2 = (f32x4_t){0.f, 0.f, 0.f, 0.f};
#pragma unroll
        for (int kb = 0; kb < 8; ++kb) {
            const bf16x8_t Af = *reinterpret_cast<const bf16x8_t*>(
                &wb[r * 264 + kb * 32 + q * 8]);
            const bf16x8_t Bf = *reinterpret_cast<const bf16x8_t*>(
                &wsb[PK_NPW2 + (kb * 64 + lane) * 8]);
            acc2 = __builtin_amdgcn_mfma_f32_16x16x32_bf16(Af, Bf, acc2, 0, 0, 0);
        }
        if (r < 12) {
            const float b2 = npb2[r];
#pragma unroll
            for (int i = 0; i < 4; ++i) {
                const int gn = n16 + q * 4 + i;
                if (gn < NN) out[gn * 12 + r] = acc2[i] + b2;
            }
        }
    }

    // pp L1: z2 = silu(h @ ppW1 + ppb1) -> wb stride 136 (z1 consumed)
    {
        f32x4_t acc[8];
#pragma unroll
        for (int ct = 0; ct < 8; ++ct) acc[ct] = (f32x4_t){0.f, 0.f, 0.f, 0.f};
#pragma unroll
        for (int kb = 0; kb < 4; ++kb) {
#pragma unroll
            for (int ct = 0; ct < 8; ++ct) {
                const bf16x8_t Bf = *reinterpret_cast<const bf16x8_t*>(
                    &wsb[PK_PPW1 + ((ct * 4 + kb) * 64 + lane) * 8]);
                acc[ct] = __builtin_amdgcn_mfma_f32_16x16x32_bf16(
                    Ah[kb], Bf, acc[ct], 0, 0, 0);
            }
        }
#pragma unroll
        for (int ct = 0; ct < 8; ++ct) {
            const int col = ct * 16 + r;
            const float b1 = ppb1[col];
#pragma unroll
            for (int i = 0; i < 4; ++i)
                wb[(q * 4 + i) * 136 + col] =
                    __float2bfloat16(silu_f(acc[ct][i] + b1));
        }
    }

    // pp L2: pos_pred = z2 @ ppW2 + ppb2 (K=128 -> 4 kb)
    {
        f32x4_t acc2 = (f32x4_t){0.f, 0.f, 0.f, 0.f};
#pragma unroll
        for (int kb = 0; kb < 4; ++kb) {
            const bf16x8_t Af = *reinterpret_cast<const bf16x8_t*>(
                &wb[r * 136 + kb * 32 + q * 8]);
            const bf16x8_t Bf = *reinterpret_cast<const bf16x8_t*>(
                &wsb[PK_PPW2 + (kb * 64 + lane) * 8]);
            acc2 = __builtin_amdgcn_mfma_f32_16x16x32_bf16(Af, Bf, acc2, 0, 0, 0);
        }
        if (r < 3) {
            const float b2 = ppb2[r];
#pragma unroll
            for (int i = 0; i < 4; ++i) {
                const int gn = n16 + q * 4 + i;
                if (gn < NN) out[NN * 12 + gn * 3 + r] = acc2[i] + b2;
            }
        }
    }
}

// ---------------------------------------------------------------------------
extern "C" void kernel_launch(void* const* d_in, const int* in_sizes, int n_in,
                              void* d_out, int out_size, void* d_ws, size_t ws_size,
                              hipStream_t stream) {
    const float* x      = (const float*)d_in[0];
    const float* t      = (const float*)d_in[4];
    const float* topo   = (const float*)d_in[5];
    const float* stab   = (const float*)d_in[6];
    const float* sust   = (const float*)d_in[7];
    const int*   batch  = (const int*)d_in[8];
    const float* Wn     = (const float*)d_in[9];
    const float* bn     = (const float*)d_in[10];
    const float* tmW1   = (const float*)d_in[13];
    const float* tmb1   = (const float*)d_in[14];
    const float* tmW2   = (const float*)d_in[15];
    const float* tmb2   = (const float*)d_in[16];
    const float* topoW1 = (const float*)d_in[17];
    const float* topob1 = (const float*)d_in[18];
    const float* topoW2 = (const float*)d_in[19];
    const float* topob2 = (const float*)d_in[20];
    const float* stabW1 = (const float*)d_in[21];
    const float* stabb1 = (const float*)d_in[22];
    const float* stabW2 = (const float*)d_in[23];
    const float* stabb2 = (const float*)d_in[24];
    const float* sustW1 = (const float*)d_in[25];
    const float* sustb1 = (const float*)d_in[26];
    const float* sustW2 = (const float*)d_in[27];
    const float* sustb2 = (const float*)d_in[28];
    const float* combW1 = (const float*)d_in[29];
    const float* combb1 = (const float*)d_in[30];
    const float* combW2 = (const float*)d_in[31];
    const float* combb2 = (const float*)d_in[32];
    const float* Wv     = (const float*)d_in[35];
    const float* Wo     = (const float*)d_in[36];
    const float* bo     = (const float*)d_in[37];
    const float* npW1   = (const float*)d_in[44];
    const float* npb1   = (const float*)d_in[45];
    const float* npW2   = (const float*)d_in[46];
    const float* npb2   = (const float*)d_in[47];
    const float* ppW1   = (const float*)d_in[48];
    const float* ppb1   = (const float*)d_in[49];
    const float* ppW2   = (const float*)d_in[50];
    const float* ppb2   = (const float*)d_in[51];

    hbf16* wsb = (hbf16*)d_ws;
    float* out = (float*)d_out;

    pack_kernel<<<232, 256, 0, stream>>>(npW1, npW2, ppW1, ppW2, Wn, wsb);

    fused_kernel<<<(NN + 63) / 64, 256, 0, stream>>>(
        x, batch, t, topo, stab, sust,
        tmW1, tmb1, tmW2, tmb2,
        topoW1, topob1, topoW2, topob2,
        stabW1, stabb1, stabW2, stabb2,
        sustW1, sustb1, sustW2, sustb2,
        combW1, combb1, combW2, combb2,
        Wv, Wo, bo, bn, npb1, npb2, ppb1, ppb2,
        wsb, out);
}

// Round 6
// 203.020 us; speedup vs baseline: 1.2568x; 1.2568x over previous
//
#include <hip/hip_runtime.h>
#include <hip/hip_bf16.h>

#define NN 20000
#define GG 128

typedef __bf16 bf16x8_t __attribute__((ext_vector_type(8)));
typedef float  f32x4_t  __attribute__((ext_vector_type(4)));
typedef __hip_bfloat16 hbf16;

// packed-weight table in ws (bf16-element offsets)
#define PK_NPW1 0       // 32768 : npW1 B-frags (16 ct x 4 kb x 64 lane x 8)
#define PK_PPW1 32768   // 16384 : ppW1 (8 ct x 4 kb x 64 x 8)
#define PK_NPW2 49152   //  4096 : npW2 (8 kb x 64 x 8), cols>=12 zero
#define PK_PPW2 53248   //  2048 : ppW2 (4 kb x 64 x 8), cols>=3 zero
#define PK_WN   55296   //  4096 : Wn   (8 ct x 64 x 8), K padded 12->32
// total 59392 bf16; gadd fp32[128][128] lives after it
#define GADD_OFF 59392  // bf16 elems -> float* = (float*)(wsb + GADD_OFF)

__device__ __forceinline__ float silu_f(float v) {
    return v * __builtin_amdgcn_rcpf(1.0f + __expf(-v));
}

// ---------------------------------------------------------------------------
// Kernel 1: blocks [0,128): per-graph gadd pipeline.
//           blocks [128,360): pack weights into MFMA B-fragment order.
// ---------------------------------------------------------------------------
__global__ __launch_bounds__(256) void prep_kernel(
        const float* __restrict__ t, const float* __restrict__ topo,
        const float* __restrict__ stab, const float* __restrict__ sust,
        const float* __restrict__ tmW1, const float* __restrict__ tmb1,
        const float* __restrict__ tmW2, const float* __restrict__ tmb2,
        const float* __restrict__ topoW1, const float* __restrict__ topob1,
        const float* __restrict__ topoW2, const float* __restrict__ topob2,
        const float* __restrict__ stabW1, const float* __restrict__ stabb1,
        const float* __restrict__ stabW2, const float* __restrict__ stabb2,
        const float* __restrict__ sustW1, const float* __restrict__ sustb1,
        const float* __restrict__ sustW2, const float* __restrict__ sustb2,
        const float* __restrict__ combW1, const float* __restrict__ combb1,
        const float* __restrict__ combW2, const float* __restrict__ combb2,
        const float* __restrict__ Wv, const float* __restrict__ Wo,
        const float* __restrict__ bo,
        const float* __restrict__ npW1, const float* __restrict__ npW2,
        const float* __restrict__ ppW1, const float* __restrict__ ppW2,
        const float* __restrict__ Wn,
        float* __restrict__ gadd, hbf16* __restrict__ wsb) {
    const int tid = threadIdx.x;

    if (blockIdx.x >= GG) {
        // ---------------- packing part ----------------
        const int s = (blockIdx.x - GG) * 256 + tid;
        if (s < 32768) {                       // npW1: [128,256]
            const int p = s;
            const int j = p & 7, l = (p >> 3) & 63, kb = (p >> 9) & 3, ct = p >> 11;
            const int k = kb * 32 + ((l >> 4) << 3) + j;
            const int n = ct * 16 + (l & 15);
            wsb[PK_NPW1 + p] = __float2bfloat16(npW1[k * 256 + n]);
        } else if (s < 49152) {                // ppW1: [128,128]
            const int p = s - 32768;
            const int j = p & 7, l = (p >> 3) & 63, kb = (p >> 9) & 3, ct = p >> 11;
            const int k = kb * 32 + ((l >> 4) << 3) + j;
            const int n = ct * 16 + (l & 15);
            wsb[PK_PPW1 + p] = __float2bfloat16(ppW1[k * 128 + n]);
        } else if (s < 53248) {                // npW2: [256,12] -> padded N=16
            const int p = s - 49152;
            const int j = p & 7, l = (p >> 3) & 63, kb = p >> 9;
            const int k = kb * 32 + ((l >> 4) << 3) + j;
            const int n = l & 15;
            wsb[PK_NPW2 + p] = __float2bfloat16(n < 12 ? npW2[k * 12 + n] : 0.0f);
        } else if (s < 55296) {                // ppW2: [128,3] -> padded N=16
            const int p = s - 53248;
            const int j = p & 7, l = (p >> 3) & 63, kb = p >> 9;
            const int k = kb * 32 + ((l >> 4) << 3) + j;
            const int n = l & 15;
            wsb[PK_PPW2 + p] = __float2bfloat16(n < 3 ? ppW2[k * 3 + n] : 0.0f);
        } else if (s < 59392) {                // Wn: [12,128] -> K padded to 32
            const int p = s - 55296;
            const int j = p & 7, l = (p >> 3) & 63, ct = p >> 9;
            const int k = ((l >> 4) << 3) + j;
            const int n = ct * 16 + (l & 15);
            wsb[PK_WN + p] = __float2bfloat16(k < 12 ? Wn[k * 128 + n] : 0.0f);
        }
        return;
    }

    // ---------------- graph pipeline part ----------------
    __shared__ float s_te[128];
    __shared__ float s_th1[256];
    __shared__ float s_tef[128];
    __shared__ float s_l1[64];
    __shared__ float s_cat[64];
    __shared__ float s_c1[64];
    __shared__ float s_cond[64];
    __shared__ float s_v[128];
    __shared__ float s_red[256];

    const int g = blockIdx.x;

    if (tid < 128) {
        const float tval = t[g];
        const int i = tid & 63;
        const float fr = __expf(-(float)i * 0.14619587892025688f);
        const float arg = tval * fr;
        s_te[tid] = (tid < 64) ? sinf(arg) : cosf(arg);
    } else if (tid < 192) {
        const int c = tid - 128;
        if (c < 32) {
            float acc = topob1[c];
            for (int k = 0; k < 7; ++k)
                acc += topo[g * 7 + k] * topoW1[k * 32 + c];
            s_l1[c] = silu_f(acc);
        } else if (c < 48) {
            const int j = c - 32;
            float acc = stabb1[j];
            for (int k = 0; k < 2; ++k)
                acc += stab[g * 2 + k] * stabW1[k * 16 + j];
            s_l1[c] = silu_f(acc);
        } else {
            const int j = c - 48;
            float acc = sustb1[j];
            for (int k = 0; k < 3; ++k)
                acc += sust[g * 3 + k] * sustW1[k * 16 + j];
            s_l1[c] = silu_f(acc);
        }
    }
    __syncthreads();

    // time MLP layer 1 [128]->[256]
    {
        float acc = tmb1[tid];
#pragma unroll 16
        for (int k = 0; k < 128; ++k)
            acc += s_te[k] * tmW1[k * 256 + tid];
        s_th1[tid] = silu_f(acc);
    }
    __syncthreads();

    // time MLP layer 2 [256]->[128], split-k 2-way
    {
        const int j = tid & 127, half = tid >> 7;
        float acc = 0.0f;
#pragma unroll 16
        for (int kk = 0; kk < 128; ++kk)
            acc += s_th1[half * 128 + kk] * tmW2[(half * 128 + kk) * 128 + j];
        s_red[tid] = acc;
    }
    __syncthreads();

    if (tid < 128) {
        s_tef[tid] = tmb2[tid] + s_red[tid] + s_red[tid + 128];
    } else if (tid < 192) {
        const int c = tid - 128;
        if (c < 32) {
            float acc = topob2[c];
            for (int k = 0; k < 32; ++k)
                acc += s_l1[k] * topoW2[k * 32 + c];
            s_cat[c] = acc;
        } else if (c < 48) {
            const int j = c - 32;
            float acc = stabb2[j];
            for (int k = 0; k < 16; ++k)
                acc += s_l1[32 + k] * stabW2[k * 16 + j];
            s_cat[c] = acc;
        } else {
            const int j = c - 48;
            float acc = sustb2[j];
            for (int k = 0; k < 16; ++k)
                acc += s_l1[48 + k] * sustW2[k * 16 + j];
            s_cat[c] = acc;
        }
    }
    __syncthreads();

    // comb layer 1, split-k 4-way
    {
        const int j = tid & 63, part = tid >> 6;
        float acc = 0.0f;
#pragma unroll
        for (int kk = 0; kk < 16; ++kk)
            acc += s_cat[part * 16 + kk] * combW1[(part * 16 + kk) * 64 + j];
        s_red[tid] = acc;
    }
    __syncthreads();
    if (tid < 64)
        s_c1[tid] = silu_f(combb1[tid] + s_red[tid] + s_red[tid + 64] +
                           s_red[tid + 128] + s_red[tid + 192]);
    __syncthreads();

    // comb layer 2, split-k 4-way
    {
        const int j = tid & 63, part = tid >> 6;
        float acc = 0.0f;
#pragma unroll
        for (int kk = 0; kk < 16; ++kk)
            acc += s_c1[part * 16 + kk] * combW2[(part * 16 + kk) * 64 + j];
        s_red[tid] = acc;
    }
    __syncthreads();
    if (tid < 64)
        s_cond[tid] = combb2[tid] + s_red[tid] + s_red[tid + 64] +
                      s_red[tid + 128] + s_red[tid + 192];
    __syncthreads();

    // v = cond @ Wv, split-k 2-way
    {
        const int j = tid & 127, half = tid >> 7;
        float acc = 0.0f;
#pragma unroll 16
        for (int kk = 0; kk < 32; ++kk)
            acc += s_cond[half * 32 + kk] * Wv[(half * 32 + kk) * 128 + j];
        s_red[tid] = acc;
    }
    __syncthreads();
    if (tid < 128) s_v[tid] = s_red[tid] + s_red[tid + 128];
    __syncthreads();

    // a = v @ Wo + bo ; gadd = 6*(a + silu(tef))
    {
        const int j = tid & 127, half = tid >> 7;
        float acc = 0.0f;
#pragma unroll 16
        for (int kk = 0; kk < 64; ++kk)
            acc += s_v[half * 64 + kk] * Wo[(half * 64 + kk) * 128 + j];
        s_red[tid] = acc;
    }
    __syncthreads();
    if (tid < 128)
        gadd[g * 128 + tid] =
            6.0f * (bo[tid] + s_red[tid] + s_red[tid + 128] + silu_f(s_tef[tid]));
}

// ---------------------------------------------------------------------------
// Kernel 2: per-node MLPs, LDS-staged weights.  64 nodes/block, 256 threads
// (4 waves x 16 nodes).  All weight fragments pass through LDS via coalesced
// bulk copies (pipelined HBM/L2), then ds_read_b128 feeds MFMA.
// MFMA contract (16x16x32 bf16), q=lane>>4, r=lane&15:
//   A[m=r][k=q*8+j]   B[k=q*8+j][n=r]   D[m=q*4+i][n=r]
// ---------------------------------------------------------------------------
#define NGS 8   // staged gadd rows per block

__global__ __launch_bounds__(256) void node_kernel(
        const float* __restrict__ x, const int* __restrict__ batch,
        const float* __restrict__ bn,
        const float* __restrict__ npb1, const float* __restrict__ npb2,
        const float* __restrict__ ppb1, const float* __restrict__ ppb2,
        const float* __restrict__ gadd, const hbf16* __restrict__ wsb,
        float* __restrict__ out) {
    __shared__ __align__(16) hbf16 s_w[8192];            // 16 KB weight chunk
    __shared__ __align__(16) hbf16 tbuf[4 * 16 * 264];   // per-wave h/z1/z2
    __shared__ float s_gadd[NGS * 128];                  // 4 KB
    __shared__ float s_bias[528];                        // bn|npb1|npb2|ppb1|ppb2
    __shared__ int   s_bi[64];

    const int tid  = threadIdx.x;
    const int nb   = blockIdx.x * 64;
    const int w    = tid >> 6;
    const int lane = tid & 63;
    const int q    = lane >> 4;
    const int r    = lane & 15;
    const int n16  = nb + w * 16;

    hbf16* wb = tbuf + w * (16 * 264);

    // ---- stage 0: batch window, g0, biases, gadd rows, Wn frags
    if (tid < 64) {
        int gn = nb + tid;
        if (gn > NN - 1) gn = NN - 1;
        s_bi[tid] = batch[gn];
    }
    {   // biases: 528 floats in two rounds
        int i = tid;
        if (i < 128) s_bias[i] = bn[i];
        else if (i < 384) s_bias[i] = npb1[i - 128];
        else if (i < 396) s_bias[i] = npb2[i - 384];
        else if (i < 524) s_bias[i] = ppb1[i - 396];
        else if (i < 527) s_bias[i] = ppb2[i - 524];
        i = tid + 256;
        if (i < 384) s_bias[i] = npb1[i - 128];
        else if (i < 396) s_bias[i] = npb2[i - 384];
        else if (i < 524) s_bias[i] = ppb1[i - 396];
        else if (i < 527) s_bias[i] = ppb2[i - 524];
    }
    {   // Wn B-frags: 4096 bf16 = 512 uint4
        const uint4* src = reinterpret_cast<const uint4*>(wsb + PK_WN);
        uint4* dst = reinterpret_cast<uint4*>(s_w);
        for (int i = tid; i < 512; i += 256) dst[i] = src[i];
    }
    __syncthreads();   // s_bi ready (needed for g0 below)

    const int g0 = s_bi[0];
    {   // gadd rows g0..g0+7 (clamped): 1024 floats
        for (int i = tid; i < NGS * 128; i += 256) {
            int gr = g0 + (i >> 7);
            if (gr > GG - 1) gr = GG - 1;
            s_gadd[i] = gadd[gr * 128 + (i & 127)];
        }
    }

    // ---- A-frag of x (M=16 nodes, K=12 padded to 32) — independent global loads
    bf16x8_t Ax;
    {
        const int node = n16 + r;
        float xv[8];
#pragma unroll
        for (int j = 0; j < 8; ++j) xv[j] = 0.0f;
        if (node < NN) {
            if (q == 0) {
                const float4 a = *reinterpret_cast<const float4*>(x + node * 12);
                const float4 b = *reinterpret_cast<const float4*>(x + node * 12 + 4);
                xv[0] = a.x; xv[1] = a.y; xv[2] = a.z; xv[3] = a.w;
                xv[4] = b.x; xv[5] = b.y; xv[6] = b.z; xv[7] = b.w;
            } else if (q == 1) {
                const float4 a = *reinterpret_cast<const float4*>(x + node * 12 + 8);
                xv[0] = a.x; xv[1] = a.y; xv[2] = a.z; xv[3] = a.w;
            }
        }
#pragma unroll
        for (int j = 0; j < 8; ++j) {
            const hbf16 tv = __float2bfloat16(xv[j]);
            Ax[j] = *reinterpret_cast<const __bf16*>(&tv);
        }
    }
    __syncthreads();   // s_w(Wn), s_gadd, s_bias ready

    // ---- h = x@Wn + bn + gadd  -> wb stride 136
    {
        f32x4_t hacc[8];
#pragma unroll
        for (int ct = 0; ct < 8; ++ct) {
            const bf16x8_t Bf = *reinterpret_cast<const bf16x8_t*>(
                &s_w[(ct * 64 + lane) * 8]);
            hacc[ct] = __builtin_amdgcn_mfma_f32_16x16x32_bf16(
                Ax, Bf, (f32x4_t){0.f, 0.f, 0.f, 0.f}, 0, 0, 0);
        }
#pragma unroll
        for (int ct = 0; ct < 8; ++ct) {
            const int n = ct * 16 + r;
            const float bv = s_bias[n];
#pragma unroll
            for (int i = 0; i < 4; ++i) {
                const int nl = w * 16 + q * 4 + i;
                const int gi = s_bi[nl] - g0;
                float ga;
                if (gi < NGS) ga = s_gadd[gi * 128 + n];
                else          ga = gadd[(g0 + gi) * 128 + n];
                wb[(q * 4 + i) * 136 + n] = __float2bfloat16(hacc[ct][i] + bv + ga);
            }
        }
    }

    // read h back as A-frags (wave-local LDS: in-order, no barrier)
    bf16x8_t Ah[4];
#pragma unroll
    for (int kb = 0; kb < 4; ++kb)
        Ah[kb] = *reinterpret_cast<const bf16x8_t*>(
            &wb[r * 136 + kb * 32 + q * 8]);

    // ---- np L1: z1 = silu(h @ npW1 + npb1), 4 chunks of 4 ct (16 KB each)
    for (int c = 0; c < 4; ++c) {
        __syncthreads();   // previous s_w use done
        {
            const uint4* src = reinterpret_cast<const uint4*>(wsb + PK_NPW1 + c * 8192);
            uint4* dst = reinterpret_cast<uint4*>(s_w);
            for (int i = tid; i < 1024; i += 256) dst[i] = src[i];
        }
        __syncthreads();
#pragma unroll
        for (int ci = 0; ci < 4; ++ci) {
            f32x4_t acc = (f32x4_t){0.f, 0.f, 0.f, 0.f};
#pragma unroll
            for (int kb = 0; kb < 4; ++kb) {
                const bf16x8_t Bf = *reinterpret_cast<const bf16x8_t*>(
                    &s_w[((ci * 4 + kb) * 64 + lane) * 8]);
                acc = __builtin_amdgcn_mfma_f32_16x16x32_bf16(Ah[kb], Bf, acc, 0, 0, 0);
            }
            const int ct = c * 4 + ci;
            const int col = ct * 16 + r;
            const float b1 = s_bias[128 + col];
#pragma unroll
            for (int i = 0; i < 4; ++i)
                wb[(q * 4 + i) * 264 + col] = __float2bfloat16(silu_f(acc[i] + b1));
        }
    }

    // ---- np L2: node_pred = z1 @ npW2 + npb2
    __syncthreads();
    {
        const uint4* src = reinterpret_cast<const uint4*>(wsb + PK_NPW2);
        uint4* dst = reinterpret_cast<uint4*>(s_w);
        for (int i = tid; i < 512; i += 256) dst[i] = src[i];
    }
    __syncthreads();
    {
        f32x4_t acc2 = (f32x4_t){0.f, 0.f, 0.f, 0.f};
#pragma unroll
        for (int kb = 0; kb < 8; ++kb) {
            const bf16x8_t Af = *reinterpret_cast<const bf16x8_t*>(
                &wb[r * 264 + kb * 32 + q * 8]);
            const bf16x8_t Bf = *reinterpret_cast<const bf16x8_t*>(
                &s_w[(kb * 64 + lane) * 8]);
            acc2 = __builtin_amdgcn_mfma_f32_16x16x32_bf16(Af, Bf, acc2, 0, 0, 0);
        }
        if (r < 12) {
            const float b2 = s_bias[384 + r];
#pragma unroll
            for (int i = 0; i < 4; ++i) {
                const int gn = n16 + q * 4 + i;
                if (gn < NN) out[gn * 12 + r] = acc2[i] + b2;
            }
        }
    }

    // ---- pp L1: z2 = silu(h @ ppW1 + ppb1), 2 chunks of 4 ct
    for (int c = 0; c < 2; ++c) {
        __syncthreads();
        {
            const uint4* src = reinterpret_cast<const uint4*>(wsb + PK_PPW1 + c * 8192);
            uint4* dst = reinterpret_cast<uint4*>(s_w);
            for (int i = tid; i < 1024; i += 256) dst[i] = src[i];
        }
        __syncthreads();
#pragma unroll
        for (int ci = 0; ci < 4; ++ci) {
            f32x4_t acc = (f32x4_t){0.f, 0.f, 0.f, 0.f};
#pragma unroll
            for (int kb = 0; kb < 4; ++kb) {
                const bf16x8_t Bf = *reinterpret_cast<const bf16x8_t*>(
                    &s_w[((ci * 4 + kb) * 64 + lane) * 8]);
                acc = __builtin_amdgcn_mfma_f32_16x16x32_bf16(Ah[kb], Bf, acc, 0, 0, 0);
            }
            const int ct = c * 4 + ci;
            const int col = ct * 16 + r;
            const float b1 = s_bias[396 + col];
#pragma unroll
            for (int i = 0; i < 4; ++i)
                wb[(q * 4 + i) * 136 + col] = __float2bfloat16(silu_f(acc[i] + b1));
        }
    }

    // ---- pp L2: pos_pred = z2 @ ppW2 + ppb2
    __syncthreads();
    {
        const uint4* src = reinterpret_cast<const uint4*>(wsb + PK_PPW2);
        uint4* dst = reinterpret_cast<uint4*>(s_w);
        for (int i = tid; i < 256; i += 256) dst[i] = src[i];
    }
    __syncthreads();
    {
        f32x4_t acc2 = (f32x4_t){0.f, 0.f, 0.f, 0.f};
#pragma unroll
        for (int kb = 0; kb < 4; ++kb) {
            const bf16x8_t Af = *reinterpret_cast<const bf16x8_t*>(
                &wb[r * 136 + kb * 32 + q * 8]);
            const bf16x8_t Bf = *reinterpret_cast<const bf16x8_t*>(
                &s_w[(kb * 64 + lane) * 8]);
            acc2 = __builtin_amdgcn_mfma_f32_16x16x32_bf16(Af, Bf, acc2, 0, 0, 0);
        }
        if (r < 3) {
            const float b2 = s_bias[524 + r];
#pragma unroll
            for (int i = 0; i < 4; ++i) {
                const int gn = n16 + q * 4 + i;
                if (gn < NN) out[NN * 12 + gn * 3 + r] = acc2[i] + b2;
            }
        }
    }
}

// ---------------------------------------------------------------------------
extern "C" void kernel_launch(void* const* d_in, const int* in_sizes, int n_in,
                              void* d_out, int out_size, void* d_ws, size_t ws_size,
                              hipStream_t stream) {
    const float* x      = (const float*)d_in[0];
    const float* t      = (const float*)d_in[4];
    const float* topo   = (const float*)d_in[5];
    const float* stab   = (const float*)d_in[6];
    const float* sust   = (const float*)d_in[7];
    const int*   batch  = (const int*)d_in[8];
    const float* Wn     = (const float*)d_in[9];
    const float* bn     = (const float*)d_in[10];
    const float* tmW1   = (const float*)d_in[13];
    const float* tmb1   = (const float*)d_in[14];
    const float* tmW2   = (const float*)d_in[15];
    const float* tmb2   = (const float*)d_in[16];
    const float* topoW1 = (const float*)d_in[17];
    const float* topob1 = (const float*)d_in[18];
    const float* topoW2 = (const float*)d_in[19];
    const float* topob2 = (const float*)d_in[20];
    const float* stabW1 = (const float*)d_in[21];
    const float* stabb1 = (const float*)d_in[22];
    const float* stabW2 = (const float*)d_in[23];
    const float* stabb2 = (const float*)d_in[24];
    const float* sustW1 = (const float*)d_in[25];
    const float* sustb1 = (const float*)d_in[26];
    const float* sustW2 = (const float*)d_in[27];
    const float* sustb2 = (const float*)d_in[28];
    const float* combW1 = (const float*)d_in[29];
    const float* combb1 = (const float*)d_in[30];
    const float* combW2 = (const float*)d_in[31];
    const float* combb2 = (const float*)d_in[32];
    const float* Wv     = (const float*)d_in[35];
    const float* Wo     = (const float*)d_in[36];
    const float* bo     = (const float*)d_in[37];
    const float* npW1   = (const float*)d_in[44];
    const float* npb1   = (const float*)d_in[45];
    const float* npW2   = (const float*)d_in[46];
    const float* npb2   = (const float*)d_in[47];
    const float* ppW1   = (const float*)d_in[48];
    const float* ppb1   = (const float*)d_in[49];
    const float* ppW2   = (const float*)d_in[50];
    const float* ppb2   = (const float*)d_in[51];

    hbf16* wsb = (hbf16*)d_ws;
    float* gadd = (float*)(wsb + GADD_OFF);
    float* out = (float*)d_out;

    prep_kernel<<<GG + 232, 256, 0, stream>>>(
        t, topo, stab, sust,
        tmW1, tmb1, tmW2, tmb2,
        topoW1, topob1, topoW2, topob2,
        stabW1, stabb1, stabW2, stabb2,
        sustW1, sustb1, sustW2, sustb2,
        combW1, combb1, combW2, combb2,
        Wv, Wo, bo,
        npW1, npW2, ppW1, ppW2, Wn,
        gadd, wsb);

    node_kernel<<<(NN + 63) / 64, 256, 0, stream>>>(
        x, batch, bn, npb1, npb2, ppb1, ppb2, gadd, wsb, out);
}

// Round 8
// 192.485 us; speedup vs baseline: 1.3256x; 1.0547x over previous
//
#include <hip/hip_runtime.h>
#include <hip/hip_bf16.h>

#define NN 20000
#define GG 128

typedef __bf16 bf16x8_t __attribute__((ext_vector_type(8)));
typedef float  f32x4_t  __attribute__((ext_vector_type(4)));
typedef __hip_bfloat16 hbf16;

// packed-weight table in ws (bf16-element offsets)
#define PK_NPW1 0       // 32768 : npW1 B-frags (16 ct x 4 kb x 64 lane x 8)
#define PK_PPW1 32768   // 16384 : ppW1 (8 ct x 4 kb x 64 x 8)
#define PK_NPW2 49152   //  4096 : npW2 (8 kb x 64 x 8), cols>=12 zero
#define PK_PPW2 53248   //  2048 : ppW2 (4 kb x 64 x 8), cols>=3 zero
#define PK_WN   55296   //  4096 : Wn   (8 ct x 64 x 8), K padded 12->32
#define GADD_OFF 59392  // then gadd fp32[128][128]

__device__ __forceinline__ float silu_f(float v) {
    return v * __builtin_amdgcn_rcpf(1.0f + __expf(-v));
}

// async HBM->LDS copy: per wave, per_wave = nbytes/4 bytes in 1024B issues
// (64 lanes x 16B).  dst/src 16B aligned; LDS dest order = lane order (the
// global_load_lds wave-uniform-base contract).
__device__ __forceinline__ void cp_async(hbf16* dst, const hbf16* src,
                                         int nbytes, int w, int lane) {
    const int per_wave = nbytes >> 2;   // 4 waves
    const char* g = (const char*)src + w * per_wave + lane * 16;
    char* l = (char*)dst + w * per_wave + lane * 16;
    for (int j = 0; j < per_wave; j += 1024)
        __builtin_amdgcn_global_load_lds(
            (__attribute__((address_space(1))) void*)(g + j),
            (__attribute__((address_space(3))) void*)(l + j),
            16, 0, 0);
}

// ---------------------------------------------------------------------------
// Kernel 1: blocks [0,128): per-graph gadd pipeline (512 thr, deep split-k).
//           blocks [128,244): pack weights into MFMA B-fragment order.
// ---------------------------------------------------------------------------
__global__ __launch_bounds__(512) void prep_kernel(
        const float* __restrict__ t, const float* __restrict__ topo,
        const float* __restrict__ stab, const float* __restrict__ sust,
        const float* __restrict__ tmW1, const float* __restrict__ tmb1,
        const float* __restrict__ tmW2, const float* __restrict__ tmb2,
        const float* __restrict__ topoW1, const float* __restrict__ topob1,
        const float* __restrict__ topoW2, const float* __restrict__ topob2,
        const float* __restrict__ stabW1, const float* __restrict__ stabb1,
        const float* __restrict__ stabW2, const float* __restrict__ stabb2,
        const float* __restrict__ sustW1, const float* __restrict__ sustb1,
        const float* __restrict__ sustW2, const float* __restrict__ sustb2,
        const float* __restrict__ combW1, const float* __restrict__ combb1,
        const float* __restrict__ combW2, const float* __restrict__ combb2,
        const float* __restrict__ Wv, const float* __restrict__ Wo,
        const float* __restrict__ bo,
        const float* __restrict__ npW1, const float* __restrict__ npW2,
        const float* __restrict__ ppW1, const float* __restrict__ ppW2,
        const float* __restrict__ Wn,
        float* __restrict__ gadd, hbf16* __restrict__ wsb) {
    const int tid = threadIdx.x;

    if (blockIdx.x >= GG) {
        const int s = (blockIdx.x - GG) * 512 + tid;
        if (s < 32768) {                       // npW1: [128,256]
            const int p = s;
            const int j = p & 7, l = (p >> 3) & 63, kb = (p >> 9) & 3, ct = p >> 11;
            const int k = kb * 32 + ((l >> 4) << 3) + j;
            const int n = ct * 16 + (l & 15);
            wsb[PK_NPW1 + p] = __float2bfloat16(npW1[k * 256 + n]);
        } else if (s < 49152) {                // ppW1: [128,128]
            const int p = s - 32768;
            const int j = p & 7, l = (p >> 3) & 63, kb = (p >> 9) & 3, ct = p >> 11;
            const int k = kb * 32 + ((l >> 4) << 3) + j;
            const int n = ct * 16 + (l & 15);
            wsb[PK_PPW1 + p] = __float2bfloat16(ppW1[k * 128 + n]);
        } else if (s < 53248) {                // npW2: [256,12] -> N padded 16
            const int p = s - 49152;
            const int j = p & 7, l = (p >> 3) & 63, kb = p >> 9;
            const int k = kb * 32 + ((l >> 4) << 3) + j;
            const int n = l & 15;
            wsb[PK_NPW2 + p] = __float2bfloat16(n < 12 ? npW2[k * 12 + n] : 0.0f);
        } else if (s < 55296) {                // ppW2: [128,3] -> N padded 16
            const int p = s - 53248;
            const int j = p & 7, l = (p >> 3) & 63, kb = p >> 9;
            const int k = kb * 32 + ((l >> 4) << 3) + j;
            const int n = l & 15;
            wsb[PK_PPW2 + p] = __float2bfloat16(n < 3 ? ppW2[k * 3 + n] : 0.0f);
        } else if (s < 59392) {                // Wn: [12,128] -> K padded 32
            const int p = s - 55296;
            const int j = p & 7, l = (p >> 3) & 63, ct = p >> 9;
            const int k = ((l >> 4) << 3) + j;
            const int n = ct * 16 + (l & 15);
            wsb[PK_WN + p] = __float2bfloat16(k < 12 ? Wn[k * 128 + n] : 0.0f);
        }
        return;
    }

    __shared__ float s_te[128];
    __shared__ float s_th1[256];
    __shared__ float s_tef[128];
    __shared__ float s_l1[64];
    __shared__ float s_cat[64];
    __shared__ float s_c1[64];
    __shared__ float s_cond[64];
    __shared__ float s_v[128];
    __shared__ float s_red[512];

    const int g = blockIdx.x;

    if (tid < 128) {
        const float tval = t[g];
        const int i = tid & 63;
        const float fr = __expf(-(float)i * 0.14619587892025688f);
        const float arg = tval * fr;
        s_te[tid] = (tid < 64) ? sinf(arg) : cosf(arg);
    } else if (tid < 192) {
        const int c = tid - 128;
        if (c < 32) {
            float acc = topob1[c];
            for (int k = 0; k < 7; ++k)
                acc += topo[g * 7 + k] * topoW1[k * 32 + c];
            s_l1[c] = silu_f(acc);
        } else if (c < 48) {
            const int j = c - 32;
            float acc = stabb1[j];
            for (int k = 0; k < 2; ++k)
                acc += stab[g * 2 + k] * stabW1[k * 16 + j];
            s_l1[c] = silu_f(acc);
        } else {
            const int j = c - 48;
            float acc = sustb1[j];
            for (int k = 0; k < 3; ++k)
                acc += sust[g * 3 + k] * sustW1[k * 16 + j];
            s_l1[c] = silu_f(acc);
        }
    }
    __syncthreads();

    // tmW1 [128]->[256]: split-k 2
    {
        const int col = tid & 255, half = tid >> 8;
        float acc = 0.0f;
#pragma unroll 32
        for (int kk = 0; kk < 64; ++kk) {
            const int k = half * 64 + kk;
            acc += s_te[k] * tmW1[k * 256 + col];
        }
        s_red[half * 256 + col] = acc;
    }
    __syncthreads();
    if (tid < 256)
        s_th1[tid] = silu_f(tmb1[tid] + s_red[tid] + s_red[256 + tid]);
    __syncthreads();

    // tmW2 [256]->[128]: split-k 4
    {
        const int col = tid & 127, qt = tid >> 7;
        float acc = 0.0f;
#pragma unroll 32
        for (int kk = 0; kk < 64; ++kk) {
            const int k = qt * 64 + kk;
            acc += s_th1[k] * tmW2[k * 128 + col];
        }
        s_red[qt * 128 + col] = acc;
    }
    __syncthreads();
    if (tid < 128) {
        s_tef[tid] = tmb2[tid] + s_red[tid] + s_red[128 + tid] +
                     s_red[256 + tid] + s_red[384 + tid];
    } else if (tid < 192) {
        const int c = tid - 128;
        if (c < 32) {
            float acc = topob2[c];
            for (int k = 0; k < 32; ++k)
                acc += s_l1[k] * topoW2[k * 32 + c];
            s_cat[c] = acc;
        } else if (c < 48) {
            const int j = c - 32;
            float acc = stabb2[j];
            for (int k = 0; k < 16; ++k)
                acc += s_l1[32 + k] * stabW2[k * 16 + j];
            s_cat[c] = acc;
        } else {
            const int j = c - 48;
            float acc = sustb2[j];
            for (int k = 0; k < 16; ++k)
                acc += s_l1[48 + k] * sustW2[k * 16 + j];
            s_cat[c] = acc;
        }
    }
    __syncthreads();

    // comb L1: split-k 8
    {
        const int col = tid & 63, part = tid >> 6;
        float acc = 0.0f;
#pragma unroll
        for (int kk = 0; kk < 8; ++kk) {
            const int k = part * 8 + kk;
            acc += s_cat[k] * combW1[k * 64 + col];
        }
        s_red[part * 64 + col] = acc;
    }
    __syncthreads();
    if (tid < 64) {
        float a = combb1[tid];
#pragma unroll
        for (int p = 0; p < 8; ++p) a += s_red[p * 64 + tid];
        s_c1[tid] = silu_f(a);
    }
    __syncthreads();

    // comb L2: split-k 8
    {
        const int col = tid & 63, part = tid >> 6;
        float acc = 0.0f;
#pragma unroll
        for (int kk = 0; kk < 8; ++kk) {
            const int k = part * 8 + kk;
            acc += s_c1[k] * combW2[k * 64 + col];
        }
        s_red[part * 64 + col] = acc;
    }
    __syncthreads();
    if (tid < 64) {
        float a = combb2[tid];
#pragma unroll
        for (int p = 0; p < 8; ++p) a += s_red[p * 64 + tid];
        s_cond[tid] = a;
    }
    __syncthreads();

    // v = cond @ Wv: split-k 4
    {
        const int col = tid & 127, qt = tid >> 7;
        float acc = 0.0f;
#pragma unroll
        for (int kk = 0; kk < 16; ++kk) {
            const int k = qt * 16 + kk;
            acc += s_cond[k] * Wv[k * 128 + col];
        }
        s_red[qt * 128 + col] = acc;
    }
    __syncthreads();
    if (tid < 128)
        s_v[tid] = s_red[tid] + s_red[128 + tid] + s_red[256 + tid] + s_red[384 + tid];
    __syncthreads();

    // a = v @ Wo: split-k 4 ; gadd = 6*(a + bo + silu(tef))
    {
        const int col = tid & 127, qt = tid >> 7;
        float acc = 0.0f;
#pragma unroll 32
        for (int kk = 0; kk < 32; ++kk) {
            const int k = qt * 32 + kk;
            acc += s_v[k] * Wo[k * 128 + col];
        }
        s_red[qt * 128 + col] = acc;
    }
    __syncthreads();
    if (tid < 128)
        gadd[g * 128 + tid] = 6.0f * (bo[tid] + s_red[tid] + s_red[128 + tid] +
                                      s_red[256 + tid] + s_red[384 + tid] +
                                      silu_f(s_tef[tid]));
}

// ---------------------------------------------------------------------------
// Kernel 2: per-node MLPs; weights streamed HBM->LDS via global_load_lds with
// double-buffered 16KB chunks overlapped with MFMA.  64 nodes/block, 4 waves.
// MFMA contract (16x16x32 bf16), q=lane>>4, r=lane&15:
//   A[m=r][k=q*8+j]   B[k=q*8+j][n=r]   D[m=q*4+i][n=r]
// ---------------------------------------------------------------------------
#define NGS 6

__global__ __launch_bounds__(256) void node_kernel(
        const float* __restrict__ x, const int* __restrict__ batch,
        const float* __restrict__ bn,
        const float* __restrict__ npb1, const float* __restrict__ npb2,
        const float* __restrict__ ppb1, const float* __restrict__ ppb2,
        const float* __restrict__ gadd, const hbf16* __restrict__ wsb,
        float* __restrict__ out) {
    __shared__ __align__(16) hbf16 s_wA[8192];           // 16 KB
    __shared__ __align__(16) hbf16 s_wB[8192];           // 16 KB
    __shared__ __align__(16) hbf16 s_wn[4096];           // 8 KB (Wn frags)
    __shared__ __align__(16) hbf16 tbuf[4 * 16 * 264];   // 33 KB h/z1/z2
    __shared__ float s_gadd[NGS * 128];                  // 3 KB
    __shared__ float s_bias[528];                        // 2.1 KB

    const int tid  = threadIdx.x;
    const int nb   = blockIdx.x * 64;
    const int w    = tid >> 6;
    const int lane = tid & 63;
    const int q    = lane >> 4;
    const int r    = lane & 15;
    const int n16  = nb + w * 16;

    hbf16* wb = tbuf + w * (16 * 264);

    // ---- async staging: Wn frags + npW1 chunk0
    cp_async(s_wn, wsb + PK_WN, 8192, w, lane);
    cp_async(s_wA, wsb + PK_NPW1, 16384, w, lane);

    // ---- regular staged loads (drain together at S0)
    const int g0 = batch[nb];
    for (int i = tid; i < NGS * 128; i += 256) {
        int gr = g0 + (i >> 7);
        if (gr > GG - 1) gr = GG - 1;
        s_gadd[i] = gadd[gr * 128 + (i & 127)];
    }
    // biases: 528 floats — FULL coverage (r7 bug: last 16 never staged)
    for (int i = tid; i < 528; i += 256) {
        float v;
        if (i < 128) v = bn[i];
        else if (i < 384) v = npb1[i - 128];
        else if (i < 396) v = npb2[i - 384];
        else if (i < 524) v = ppb1[i - 396];
        else if (i < 527) v = ppb2[i - 524];
        else v = 0.0f;
        s_bias[i] = v;
    }

    // x A-frag (M=16, K=12 padded to 32)
    bf16x8_t Ax;
    {
        const int node = n16 + r;
        float xv[8];
#pragma unroll
        for (int j = 0; j < 8; ++j) xv[j] = 0.0f;
        if (node < NN) {
            if (q == 0) {
                const float4 a = *reinterpret_cast<const float4*>(x + node * 12);
                const float4 b = *reinterpret_cast<const float4*>(x + node * 12 + 4);
                xv[0] = a.x; xv[1] = a.y; xv[2] = a.z; xv[3] = a.w;
                xv[4] = b.x; xv[5] = b.y; xv[6] = b.z; xv[7] = b.w;
            } else if (q == 1) {
                const float4 a = *reinterpret_cast<const float4*>(x + node * 12 + 8);
                xv[0] = a.x; xv[1] = a.y; xv[2] = a.z; xv[3] = a.w;
            }
        }
#pragma unroll
        for (int j = 0; j < 8; ++j) {
            const hbf16 tv = __float2bfloat16(xv[j]);
            Ax[j] = *reinterpret_cast<const __bf16*>(&tv);
        }
    }
    int gidx[4];
#pragma unroll
    for (int i = 0; i < 4; ++i) {
        int gn = n16 + q * 4 + i;
        if (gn > NN - 1) gn = NN - 1;
        gidx[i] = batch[gn] - g0;
    }
    __syncthreads();   // S0: Wn + chunk0 + gadd + biases ready

    // ---- h = x@Wn + bn + gadd  -> wb stride 136 ; Ah regs
    bf16x8_t Ah[4];
    {
        f32x4_t hacc[8];
#pragma unroll
        for (int ct = 0; ct < 8; ++ct) {
            const bf16x8_t Bf = *reinterpret_cast<const bf16x8_t*>(
                &s_wn[(ct * 64 + lane) * 8]);
            hacc[ct] = __builtin_amdgcn_mfma_f32_16x16x32_bf16(
                Ax, Bf, (f32x4_t){0.f, 0.f, 0.f, 0.f}, 0, 0, 0);
        }
#pragma unroll
        for (int ct = 0; ct < 8; ++ct) {
            const int n = ct * 16 + r;
            const float bv = s_bias[n];
#pragma unroll
            for (int i = 0; i < 4; ++i) {
                const int gi = gidx[i];
                const float ga = (gi < NGS) ? s_gadd[gi * 128 + n]
                                            : gadd[(g0 + gi) * 128 + n];
                wb[(q * 4 + i) * 136 + n] = __float2bfloat16(hacc[ct][i] + bv + ga);
            }
        }
#pragma unroll
        for (int kb = 0; kb < 4; ++kb)
            Ah[kb] = *reinterpret_cast<const bf16x8_t*>(
                &wb[r * 136 + kb * 32 + q * 8]);
    }

    auto npL1_quad = [&](int cbase, const hbf16* sw) {
#pragma unroll
        for (int ci = 0; ci < 4; ++ci) {
            f32x4_t acc = (f32x4_t){0.f, 0.f, 0.f, 0.f};
#pragma unroll
            for (int kb = 0; kb < 4; ++kb) {
                const bf16x8_t Bf = *reinterpret_cast<const bf16x8_t*>(
                    &sw[((ci * 4 + kb) * 64 + lane) * 8]);
                acc = __builtin_amdgcn_mfma_f32_16x16x32_bf16(Ah[kb], Bf, acc, 0, 0, 0);
            }
            const int col = (cbase * 4 + ci) * 16 + r;
            const float b1 = s_bias[128 + col];
#pragma unroll
            for (int i = 0; i < 4; ++i)
                wb[(q * 4 + i) * 264 + col] = __float2bfloat16(silu_f(acc[i] + b1));
        }
    };
    auto ppL1_quad = [&](int cbase, const hbf16* sw) {
#pragma unroll
        for (int ci = 0; ci < 4; ++ci) {
            f32x4_t acc = (f32x4_t){0.f, 0.f, 0.f, 0.f};
#pragma unroll
            for (int kb = 0; kb < 4; ++kb) {
                const bf16x8_t Bf = *reinterpret_cast<const bf16x8_t*>(
                    &sw[((ci * 4 + kb) * 64 + lane) * 8]);
                acc = __builtin_amdgcn_mfma_f32_16x16x32_bf16(Ah[kb], Bf, acc, 0, 0, 0);
            }
            const int col = (cbase * 4 + ci) * 16 + r;
            const float b1 = s_bias[396 + col];
#pragma unroll
            for (int i = 0; i < 4; ++i)
                wb[(q * 4 + i) * 136 + col] = __float2bfloat16(silu_f(acc[i] + b1));
        }
    };

    // ---- streamed K-loop: issue next chunk, compute current, barrier
    cp_async(s_wB, wsb + PK_NPW1 + 8192, 16384, w, lane);
    npL1_quad(0, s_wA);
    __syncthreads();

    cp_async(s_wA, wsb + PK_NPW1 + 16384, 16384, w, lane);
    npL1_quad(1, s_wB);
    __syncthreads();

    cp_async(s_wB, wsb + PK_NPW1 + 24576, 16384, w, lane);
    npL1_quad(2, s_wA);
    __syncthreads();

    cp_async(s_wA, wsb + PK_NPW2, 8192, w, lane);
    npL1_quad(3, s_wB);
    __syncthreads();

    // np L2 from A (npW2)
    cp_async(s_wB, wsb + PK_PPW1, 16384, w, lane);
    {
        f32x4_t acc2 = (f32x4_t){0.f, 0.f, 0.f, 0.f};
#pragma unroll
        for (int kb = 0; kb < 8; ++kb) {
            const bf16x8_t Af = *reinterpret_cast<const bf16x8_t*>(
                &wb[r * 264 + kb * 32 + q * 8]);
            const bf16x8_t Bf = *reinterpret_cast<const bf16x8_t*>(
                &s_wA[(kb * 64 + lane) * 8]);
            acc2 = __builtin_amdgcn_mfma_f32_16x16x32_bf16(Af, Bf, acc2, 0, 0, 0);
        }
        if (r < 12) {
            const float b2 = s_bias[384 + r];
#pragma unroll
            for (int i = 0; i < 4; ++i) {
                const int gn = n16 + q * 4 + i;
                if (gn < NN) out[gn * 12 + r] = acc2[i] + b2;
            }
        }
    }
    __syncthreads();

    cp_async(s_wA, wsb + PK_PPW1 + 8192, 16384, w, lane);
    ppL1_quad(0, s_wB);
    __syncthreads();

    cp_async(s_wB, wsb + PK_PPW2, 4096, w, lane);
    ppL1_quad(1, s_wA);
    __syncthreads();

    // pp L2 from B (ppW2)
    {
        f32x4_t acc2 = (f32x4_t){0.f, 0.f, 0.f, 0.f};
#pragma unroll
        for (int kb = 0; kb < 4; ++kb) {
            const bf16x8_t Af = *reinterpret_cast<const bf16x8_t*>(
                &wb[r * 136 + kb * 32 + q * 8]);
            const bf16x8_t Bf = *reinterpret_cast<const bf16x8_t*>(
                &s_wB[(kb * 64 + lane) * 8]);
            acc2 = __builtin_amdgcn_mfma_f32_16x16x32_bf16(Af, Bf, acc2, 0, 0, 0);
        }
        if (r < 3) {
            const float b2 = s_bias[524 + r];
#pragma unroll
            for (int i = 0; i < 4; ++i) {
                const int gn = n16 + q * 4 + i;
                if (gn < NN) out[NN * 12 + gn * 3 + r] = acc2[i] + b2;
            }
        }
    }
}

// ---------------------------------------------------------------------------
extern "C" void kernel_launch(void* const* d_in, const int* in_sizes, int n_in,
                              void* d_out, int out_size, void* d_ws, size_t ws_size,
                              hipStream_t stream) {
    const float* x      = (const float*)d_in[0];
    const float* t      = (const float*)d_in[4];
    const float* topo   = (const float*)d_in[5];
    const float* stab   = (const float*)d_in[6];
    const float* sust   = (const float*)d_in[7];
    const int*   batch  = (const int*)d_in[8];
    const float* Wn     = (const float*)d_in[9];
    const float* bn     = (const float*)d_in[10];
    const float* tmW1   = (const float*)d_in[13];
    const float* tmb1   = (const float*)d_in[14];
    const float* tmW2   = (const float*)d_in[15];
    const float* tmb2   = (const float*)d_in[16];
    const float* topoW1 = (const float*)d_in[17];
    const float* topob1 = (const float*)d_in[18];
    const float* topoW2 = (const float*)d_in[19];
    const float* topob2 = (const float*)d_in[20];
    const float* stabW1 = (const float*)d_in[21];
    const float* stabb1 = (const float*)d_in[22];
    const float* stabW2 = (const float*)d_in[23];
    const float* stabb2 = (const float*)d_in[24];
    const float* sustW1 = (const float*)d_in[25];
    const float* sustb1 = (const float*)d_in[26];
    const float* sustW2 = (const float*)d_in[27];
    const float* sustb2 = (const float*)d_in[28];
    const float* combW1 = (const float*)d_in[29];
    const float* combb1 = (const float*)d_in[30];
    const float* combW2 = (const float*)d_in[31];
    const float* combb2 = (const float*)d_in[32];
    const float* Wv     = (const float*)d_in[35];
    const float* Wo     = (const float*)d_in[36];
    const float* bo     = (const float*)d_in[37];
    const float* npW1   = (const float*)d_in[44];
    const float* npb1   = (const float*)d_in[45];
    const float* npW2   = (const float*)d_in[46];
    const float* npb2   = (const float*)d_in[47];
    const float* ppW1   = (const float*)d_in[48];
    const float* ppb1   = (const float*)d_in[49];
    const float* ppW2   = (const float*)d_in[50];
    const float* ppb2   = (const float*)d_in[51];

    hbf16* wsb = (hbf16*)d_ws;
    float* gadd = (float*)(wsb + GADD_OFF);
    float* out = (float*)d_out;

    prep_kernel<<<GG + 116, 512, 0, stream>>>(
        t, topo, stab, sust,
        tmW1, tmb1, tmW2, tmb2,
        topoW1, topob1, topoW2, topob2,
        stabW1, stabb1, stabW2, stabb2,
        sustW1, sustb1, sustW2, sustb2,
        combW1, combb1, combW2, combb2,
        Wv, Wo, bo,
        npW1, npW2, ppW1, ppW2, Wn,
        gadd, wsb);

    node_kernel<<<(NN + 63) / 64, 256, 0, stream>>>(
        x, batch, bn, npb1, npb2, ppb1, ppb2, gadd, wsb, out);
}